// Round 17
// baseline (138.117 us; speedup 1.0000x reference)
//
#include <hip/hip_runtime.h>
#include <math.h>

typedef unsigned short u16;
typedef unsigned int u32;
typedef __bf16 bf16x8 __attribute__((ext_vector_type(8)));
typedef float f32x4 __attribute__((ext_vector_type(4)));
typedef float f32x16 __attribute__((ext_vector_type(16)));

// ---------- helpers ----------
__device__ __forceinline__ u32 f2bf(float f) {
  union { float f; u32 u; } v; v.f = f;
  u32 r = v.u + 0x7fffu + ((v.u >> 16) & 1u);
  return r >> 16;
}

__device__ __forceinline__ u32 pkbf(float a, float b) {
  u32 r;
  asm("v_cvt_pk_bf16_f32 %0, %1, %2" : "=v"(r) : "v"(a), "v"(b));
  return r;
}

// v_exp_f32 computes 2^x (log2 domain)
__device__ __forceinline__ float ex2(float x) {
  float r;
  asm("v_exp_f32 %0, %1" : "=v"(r) : "v"(x));
  return r;
}

// async global->LDS, 16B per lane. LDS dest wave-uniform base; HW adds lane*16.
__device__ __forceinline__ void gld16(const void* g, void* s) {
  __builtin_amdgcn_global_load_lds(
      reinterpret_cast<__attribute__((address_space(1))) u32*>((size_t)g),
      reinterpret_cast<__attribute__((address_space(3))) u32*>((u32)(size_t)s),
      16, 0, 0);
}

// ---------- prep: all conversions + lut + gate in ONE launch ----------
__global__ __launch_bounds__(256) void prepk(
    const float* __restrict__ query, const float* __restrict__ q_w,
    const float* __restrict__ k_w, const float* __restrict__ v_w,
    const float* __restrict__ out_w, const float* __restrict__ rel_emb,
    const float* __restrict__ grep_w, const float* __restrict__ grep_b,
    const float* __restrict__ grep_a,
    u16* __restrict__ qbf, u16* __restrict__ wqb, u16* __restrict__ wkb,
    u16* __restrict__ wvb, u16* __restrict__ wob,
    float* __restrict__ lut, float* __restrict__ gate) {
  const int bid = blockIdx.x, tid = threadIdx.x;
  if (bid < 8192) {
    const float* src; u16* dst; int i0;
    if (bid < 4096)      { src = query; dst = qbf; i0 = bid; }
    else if (bid < 5120) { src = q_w;   dst = wqb; i0 = bid - 4096; }
    else if (bid < 6144) { src = k_w;   dst = wkb; i0 = bid - 5120; }
    else if (bid < 7168) { src = v_w;   dst = wvb; i0 = bid - 6144; }
    else                 { src = out_w; dst = wob; i0 = bid - 7168; }
    const int i = i0 * 256 + tid;
    float4 v = ((const float4*)src)[i];
    uint2 o;
    o.x = f2bf(v.x) | (f2bf(v.y) << 16);
    o.y = f2bf(v.z) | (f2bf(v.w) << 16);
    ((uint2*)dst)[i] = o;
  } else if (bid < 8208) {
    const int dix = (bid - 8192) * 256 + tid;
    int rp = dix - 2048;                 // rp = s - t
    int bucket = (rp > 0) ? 16 : 0;
    int rpa = rp < 0 ? -rp : rp;
    if (rpa < 8) {
      bucket += rpa;
    } else {
      int large = 8 + (int)(logf((float)rpa * 0.125f) * (8.0f / 2.772588722239781f));
      bucket += (large < 15) ? large : 15;
    }
    const float LOG2E = 1.4426950408889634f;
#pragma unroll
    for (int h = 0; h < 16; ++h) lut[h * 4096 + dix] = rel_emb[bucket * 16 + h] * LOG2E;
  } else {
    __shared__ __align__(16) float gw[8][64];
    __shared__ float gb[8];
    __shared__ float ga[16];
    if (tid < 128) ((float4*)&gw[0][0])[tid] = ((const float4*)grep_w)[tid];
    if (tid < 8) gb[tid] = grep_b[tid];
    if (tid < 16) ga[tid] = grep_a[tid];
    __syncthreads();
    const int i = (bid - 8208) * 256 + tid;  // i = ((b*16+h)*2048 + t)
    const int t = i & 2047, h = (i >> 11) & 15, b = i >> 15;
    const float* x = query + ((size_t)t * 2 + b) * 1024 + h * 64;
    float acc[8] = {0, 0, 0, 0, 0, 0, 0, 0};
    for (int e4 = 0; e4 < 16; ++e4) {
      float4 xv = ((const float4*)x)[e4];
#pragma unroll
      for (int j = 0; j < 8; ++j)
        acc[j] += xv.x * gw[j][e4 * 4] + xv.y * gw[j][e4 * 4 + 1] +
                  xv.z * gw[j][e4 * 4 + 2] + xv.w * gw[j][e4 * 4 + 3];
    }
    float sA = acc[0] + acc[1] + acc[2] + acc[3] + gb[0] + gb[1] + gb[2] + gb[3];
    float sB = acc[4] + acc[5] + acc[6] + acc[7] + gb[4] + gb[5] + gb[6] + gb[7];
    float gA = 1.0f / (1.0f + expf(-sA));
    float gB = 1.0f / (1.0f + expf(-sB));
    gate[i] = gA * (gB * ga[h] - 1.0f) + 2.0f;
  }
}

// ---------- GEMM: fused-QKV 64x64 tiles, BK=64; A staged ONCE for NMODE weight mats ----------
// MB+mm = mode: 0 q->qa*QSC ; 1 k->kstage ; 2 v->vstage ; 3 out-proj->fout fp32
// kstage[bh][tile(64)][slot(8)][srow(32)][8] ; vstage[bh][tile(64)][slot(4)][d(64)][8]
template <int MB, int NM>
__global__ __launch_bounds__(256) void gemmk(
    const u16* __restrict__ A,
    const u16* __restrict__ W0, const u16* __restrict__ W1, const u16* __restrict__ W2,
    const float* __restrict__ b0, const float* __restrict__ b1, const float* __restrict__ b2,
    u16* __restrict__ qa, u16* __restrict__ kst, u16* __restrict__ vst,
    float* __restrict__ fout) {
  __shared__ __align__(16) u16 As[64 * 64];        // 8KB  [row][64], slot^=(row&7)
  __shared__ __align__(16) u16 Bs[NM][64 * 64];    // 8KB per mode

  const int tid = threadIdx.x;
  const int l = tid & 63;
  const int w = tid >> 6;
  const int wr = w >> 1, wc = w & 1;               // wave quadrant: rows wr*32, cols wc*32
  const int m0 = blockIdx.y * 64, n0 = blockIdx.x * 64;
  const int li = l >> 3, ls = l & 7;
  const u16* const Ws[3] = {W0, W1, W2};
  const float* const bs[3] = {b0, b1, b2};

  f32x4 acc[NM][2][2] = {};

  for (int k0 = 0; k0 < 1024; k0 += 64) {
#pragma unroll
    for (int j = 0; j < 2; ++j) {
      const int rr = w * 16 + j * 8 + li;
      const int cs = ls ^ (rr & 7);                // inverse-swizzled source slot
      gld16(A + ((size_t)(m0 + rr) << 10) + k0 + cs * 8, &As[(w * 16 + j * 8) * 64]);
#pragma unroll
      for (int mm = 0; mm < NM; ++mm)
        gld16(Ws[mm] + ((size_t)(n0 + rr) << 10) + k0 + cs * 8, &Bs[mm][(w * 16 + j * 8) * 64]);
    }
    __syncthreads();
#pragma unroll
    for (int ks = 0; ks < 2; ++ks) {
      bf16x8 af[2];
#pragma unroll
      for (int mf = 0; mf < 2; ++mf) {
        const int row = wr * 32 + mf * 16 + (l & 15);
        const int slot = (ks * 4 + (l >> 4)) ^ (row & 7);
        af[mf] = *(const bf16x8*)&As[row * 64 + slot * 8];
      }
#pragma unroll
      for (int mm = 0; mm < NM; ++mm) {
        bf16x8 bfr[2];
#pragma unroll
        for (int nf = 0; nf < 2; ++nf) {
          const int row = wc * 32 + nf * 16 + (l & 15);
          const int slot = (ks * 4 + (l >> 4)) ^ (row & 7);
          bfr[nf] = *(const bf16x8*)&Bs[mm][row * 64 + slot * 8];
        }
#pragma unroll
        for (int mf = 0; mf < 2; ++mf)
#pragma unroll
          for (int nf = 0; nf < 2; ++nf)
            acc[mm][mf][nf] = __builtin_amdgcn_mfma_f32_16x16x32_bf16(af[mf], bfr[nf], acc[mm][mf][nf], 0, 0, 0);
      }
    }
    __syncthreads();
  }

  const float QSC = 0.125f * 1.4426950408889634f;  // HD^-0.5 * log2(e): Q in log2 domain
#pragma unroll
  for (int mm = 0; mm < NM; ++mm) {
    const int mode = MB + mm;                      // compile-time
    const float* bias = bs[mm];
#pragma unroll
    for (int mf = 0; mf < 2; ++mf)
#pragma unroll
      for (int nf = 0; nf < 2; ++nf)
#pragma unroll
        for (int r = 0; r < 4; ++r) {
          const int row = m0 + wr * 32 + mf * 16 + (l >> 4) * 4 + r;  // m = t*2+b
          const int col = n0 + wc * 32 + nf * 16 + (l & 15);          // n = h*64+d
          float v = acc[mm][mf][nf][r] + bias[col];
          const int t = row >> 1, bb = row & 1, hh = col >> 6, d = col & 63;
          const size_t bh = (size_t)bb * 16 + hh;
          if (mode == 0) {
            v *= QSC;
            qa[((bh * 2048 + t) << 6) + d] = (u16)f2bf(v);
          } else if (mode == 1) {
            kst[((bh * 64 + (t >> 5)) << 11) + ((d >> 3) << 8) + ((t & 31) << 3) + (d & 7)] = (u16)f2bf(v);
          } else if (mode == 2) {
            vst[((bh * 64 + (t >> 5)) << 11) + (((t >> 3) & 3) << 9) + (d << 3) + (t & 7)] = (u16)f2bf(v);
          } else {
            fout[((size_t)row << 10) + col] = v;
          }
        }
  }
}

// ---------- flash attention v10+T5: KVBLK=64 pairing + s_setprio around MFMA clusters ----------
// Block = 128 q-rows, 4 waves (2 halves x 2 subs); wave owns TWO 32-row q-tiles over its
// 1024-KV half. LDS buffers hold a PAIR of consecutive K/V tiles; prefetch pair t+1 at top
// of pair t; two inner iterations per pair; ONE __syncthreads per pair. setprio(1) wraps
// QK^T and PV MFMA clusters (T5: independent blocks per SIMD -> scheduler favors MFMA wave).
__global__ __launch_bounds__(256, 2) void flashk(const u16* __restrict__ qa,
                                                 const u16* __restrict__ kst,
                                                 const u16* __restrict__ vst,
                                                 const float* __restrict__ lutg,
                                                 const float* __restrict__ gatew,
                                                 u16* __restrict__ aout) {
  const int B = blockIdx.x;
  const int xcd = B & 7, j = B >> 3;
  const int bh = xcd * 4 + (j >> 4);       // 4 heads per XCD (K/V L2-resident)
  const int qt = j & 15;
  const int hh = bh & 15, b = bh >> 4;
  const int tid = threadIdx.x, l = tid & 63, w = tid >> 6;
  const int half = w >> 1, sub = w & 1;
  const int hi = l >> 5, q = l & 31;
  const int q0b = qt * 128;
  const int qr0 = q0b + sub * 32;          // q-tile 0 base
  const int qr1 = q0b + 64 + sub * 32;     // q-tile 1 base

  __shared__ union {
    struct { u16 K[2][2][4096]; u16 V[2][2][4096]; } m;   // 64KB: [half][buf][pair of tiles]
    struct { float pO[2][2][32][68]; } c;                 // combine 34.8KB
  } S;
  __shared__ float pm[2][2][32], pl[2][2][32];
  __shared__ __align__(16) float slice[288];   // lut band, dix0=1920 -> s-t in [-128,160)

  for (int i = tid; i < 288; i += 256) slice[i] = lutg[hh * 4096 + 1920 + i];

  const size_t tb0 = (size_t)bh * 64;      // tile index base
  const u16* Q = qa + ((size_t)bh << 17);

  // Q B-frags + per-tile state
  bf16x8 qf[2][4];
  float g[2], m_run[2], l_run[2];
  f32x16 oacc[2][2] = {};                  // [qi][dt]
#pragma unroll
  for (int qi = 0; qi < 2; ++qi) {
    const int qg = (qi ? qr1 : qr0) + q;
#pragma unroll
    for (int mk = 0; mk < 4; ++mk)
      qf[qi][mk] = *(const bf16x8*)&Q[((size_t)qg << 6) + mk * 16 + hi * 8];
    g[qi] = gatew[((size_t)bh << 11) + qg];
    m_run[qi] = -3e38f;
    l_run[qi] = 0.0f;
  }
  const float lutm = lutg[hh * 4096];          // far-minus lut value (log2 dom)
  const float lutp = lutg[hh * 4096 + 4095];   // far-plus lut value

  // prologue: stage pair 0 (tiles 0,1 of this half) into buf 0. Linear lane*16B.
  {
    const u16* kt0 = kst + ((tb0 + half * 32) << 11) + l * 8;
    const u16* vt0 = vst + ((tb0 + half * 32) << 11) + l * 8;
    if (sub == 0) {
#pragma unroll
      for (int i = 0; i < 8; ++i) gld16(kt0 + i * 512, &S.m.K[half][0][i * 512]);
    } else {
#pragma unroll
      for (int i = 0; i < 8; ++i) gld16(vt0 + i * 512, &S.m.V[half][0][i * 512]);
    }
  }
  __syncthreads();

  for (int tp = 0; tp < 16; ++tp) {
    const int buf = tp & 1;
    // prefetch next PAIR into other buffer (two contiguous tiles = 8 linear gld16)
    if (tp < 15) {
      const u16* ktn = kst + ((tb0 + half * 32 + (tp + 1) * 2) << 11) + l * 8;
      const u16* vtn = vst + ((tb0 + half * 32 + (tp + 1) * 2) << 11) + l * 8;
      if (sub == 0) {
#pragma unroll
        for (int i = 0; i < 8; ++i) gld16(ktn + i * 512, &S.m.K[half][buf ^ 1][i * 512]);
      } else {
#pragma unroll
        for (int i = 0; i < 8; ++i) gld16(vtn + i * 512, &S.m.V[half][buf ^ 1][i * 512]);
      }
    }

#pragma unroll
    for (int st = 0; st < 2; ++st) {
      const int ts = tp * 2 + st;
      const u16* Kb = &S.m.K[half][buf][st * 2048];
      const u16* Vb = &S.m.V[half][buf][st * 2048];
      const int s0 = half * 1024 + ts * 32;

      // K frags load ONCE, serve both q-tiles
      bf16x8 kf[4];
#pragma unroll
      for (int mk = 0; mk < 4; ++mk)
        kf[mk] = *(const bf16x8*)&Kb[(mk * 2 + hi) * 256 + q * 8];

      bf16x8 pa[2][2];
#pragma unroll
      for (int qi = 0; qi < 2; ++qi) {
        const int qrb = qi ? qr1 : qr0;
        // S^T tile: C[k_local][q], k_local = (reg&3)+8*(reg>>2)+4*hi
        __builtin_amdgcn_s_setprio(1);
        f32x16 s = {};
#pragma unroll
        for (int mk = 0; mk < 4; ++mk)
          s = __builtin_amdgcn_mfma_f32_32x32x16_bf16(kf[mk], qf[qi][mk], s, 0, 0, 0);
        __builtin_amdgcn_s_setprio(0);

        const int kt = (s0 - qrb) >> 5;
        const bool far = (kt <= -4) | (kt >= 4);
        float gc = 0.0f;
        float mx;
        if (far) {
          gc = ((kt < 0) ? lutm : lutp) * g[qi];
          float t0_ = fmaxf(fmaxf(s[0], s[1]), s[2]);
          float t1_ = fmaxf(fmaxf(s[3], s[4]), s[5]);
          float t2_ = fmaxf(fmaxf(s[6], s[7]), s[8]);
          float t3_ = fmaxf(fmaxf(s[9], s[10]), s[11]);
          float t4_ = fmaxf(fmaxf(s[12], s[13]), s[14]);
          mx = fmaxf(fmaxf(fmaxf(t0_, t1_), t2_), fmaxf(fmaxf(t3_, t4_), s[15]));
          mx = fmaxf(mx, __shfl_xor(mx, 32, 64)) + gc;
        } else {
          const int sb = s0 - qrb + 128 + 4 * hi - q;
#pragma unroll
          for (int reg = 0; reg < 16; ++reg) {
            const int kloc = (reg & 3) + 8 * (reg >> 2);
            s[reg] = fmaf(g[qi], slice[sb + kloc], s[reg]);
          }
          float t0_ = fmaxf(fmaxf(s[0], s[1]), s[2]);
          float t1_ = fmaxf(fmaxf(s[3], s[4]), s[5]);
          float t2_ = fmaxf(fmaxf(s[6], s[7]), s[8]);
          float t3_ = fmaxf(fmaxf(s[9], s[10]), s[11]);
          float t4_ = fmaxf(fmaxf(s[12], s[13]), s[14]);
          mx = fmaxf(fmaxf(fmaxf(t0_, t1_), t2_), fmaxf(fmaxf(t3_, t4_), s[15]));
          mx = fmaxf(mx, __shfl_xor(mx, 32, 64));
        }
        // defer-max (T13), log2 domain threshold ~ 8*log2e
        if (!__all(mx - m_run[qi] <= 11.5f)) {
          const float mnew = fmaxf(m_run[qi], mx);
          const float sc = ex2(m_run[qi] - mnew);
          l_run[qi] *= sc;
#pragma unroll
          for (int r = 0; r < 16; ++r) { oacc[qi][0][r] *= sc; oacc[qi][1][r] *= sc; }
          m_run[qi] = mnew;
        }
        // P = 2^(S - mref), tree row-sum
        const float mref = m_run[qi] - gc;
#pragma unroll
        for (int reg = 0; reg < 16; ++reg) s[reg] = ex2(s[reg] - mref);
        {
          float r0 = (s[0] + s[1]) + (s[2] + s[3]);
          float r1 = (s[4] + s[5]) + (s[6] + s[7]);
          float r2 = (s[8] + s[9]) + (s[10] + s[11]);
          float r3 = (s[12] + s[13]) + (s[14] + s[15]);
          float rsum = (r0 + r1) + (r2 + r3);
          rsum += __shfl_xor(rsum, 32, 64);
          l_run[qi] += rsum;
        }
        // pack P -> PV B-frags (T12, shfl-proven exchange)
#pragma unroll
        for (int kh = 0; kh < 2; ++kh) {
          const int rb = kh * 8;
          const u32 X0 = pkbf(s[rb + 0], s[rb + 1]);
          const u32 X1 = pkbf(s[rb + 2], s[rb + 3]);
          const u32 Y0 = pkbf(s[rb + 4], s[rb + 5]);
          const u32 Y1 = pkbf(s[rb + 6], s[rb + 7]);
          const u32 E0 = hi ? X0 : Y0;
          const u32 E1 = hi ? X1 : Y1;
          const u32 Ep0 = (u32)__shfl_xor((int)E0, 32, 64);
          const u32 Ep1 = (u32)__shfl_xor((int)E1, 32, 64);
          union { u32 wds[4]; bf16x8 v; } pu;
          pu.wds[0] = hi ? Ep0 : X0;
          pu.wds[1] = hi ? Ep1 : X1;
          pu.wds[2] = hi ? Y0 : Ep0;
          pu.wds[3] = hi ? Y1 : Ep1;
          pa[qi][kh] = pu.v;
        }
      }
      // V frags load ONCE, serve both q-tiles
      bf16x8 vf[4];
#pragma unroll
      for (int i2 = 0; i2 < 4; ++i2) {     // i2 = dt*2+kh
        const int dt = i2 >> 1, kh = i2 & 1;
        vf[i2] = *(const bf16x8*)&Vb[(kh * 2 + hi) * 512 + dt * 256 + q * 8];
      }
      // O^T += V^T . P for both q-tiles
      __builtin_amdgcn_s_setprio(1);
#pragma unroll
      for (int qi = 0; qi < 2; ++qi)
#pragma unroll
        for (int dt = 0; dt < 2; ++dt)
#pragma unroll
          for (int kh = 0; kh < 2; ++kh)
            oacc[qi][dt] = __builtin_amdgcn_mfma_f32_32x32x16_bf16(vf[dt * 2 + kh], pa[qi][kh], oacc[qi][dt], 0, 0, 0);
      __builtin_amdgcn_s_setprio(0);
    }
    __syncthreads();   // pair t+1 staged (vmcnt drained); all waves done with buf
  }

  // ---- 2-way combine: pairs (half0,sub) <-> (half1,sub), both q-tiles ----
  __syncthreads();   // all K/V reads done; repurpose LDS union
  if (half == 1) {
    if (hi == 0) {
      pm[sub][0][q] = m_run[0]; pl[sub][0][q] = l_run[0];
      pm[sub][1][q] = m_run[1]; pl[sub][1][q] = l_run[1];
    }
#pragma unroll
    for (int qi = 0; qi < 2; ++qi)
#pragma unroll
      for (int dt = 0; dt < 2; ++dt)
#pragma unroll
        for (int g4 = 0; g4 < 4; ++g4) {
          float4 v4;
          v4.x = oacc[qi][dt][g4 * 4 + 0];
          v4.y = oacc[qi][dt][g4 * 4 + 1];
          v4.z = oacc[qi][dt][g4 * 4 + 2];
          v4.w = oacc[qi][dt][g4 * 4 + 3];
          *(float4*)&S.c.pO[sub][qi][q][dt * 32 + g4 * 8 + hi * 4] = v4;
        }
  }
  __syncthreads();
  if (half == 0) {
#pragma unroll
    for (int qi = 0; qi < 2; ++qi) {
      const float mB = pm[sub][qi][q], lB = pl[sub][qi][q];
      const float M = fmaxf(m_run[qi], mB);
      const float eA = ex2(m_run[qi] - M), eB = ex2(mB - M);
      const float inv = 1.0f / (l_run[qi] * eA + lB * eB);
      const int qg = (qi ? qr1 : qr0) + q;
#pragma unroll
      for (int dt = 0; dt < 2; ++dt)
#pragma unroll
        for (int gph = 0; gph < 4; ++gph) {
          const int d0 = dt * 32 + gph * 8 + hi * 4;
          const float4 p4 = *(const float4*)&S.c.pO[sub][qi][q][d0];
          const float o0 = (oacc[qi][dt][gph * 4 + 0] * eA + p4.x * eB) * inv;
          const float o1 = (oacc[qi][dt][gph * 4 + 1] * eA + p4.y * eB) * inv;
          const float o2 = (oacc[qi][dt][gph * 4 + 2] * eA + p4.z * eB) * inv;
          const float o3 = (oacc[qi][dt][gph * 4 + 3] * eA + p4.w * eB) * inv;
          uint2 st;
          st.x = pkbf(o0, o1);
          st.y = pkbf(o2, o3);
          *(uint2*)&aout[(((size_t)qg * 2 + b) << 10) + hh * 64 + d0] = st;
        }
    }
  }
}

// ---------- launch ----------
extern "C" void kernel_launch(void* const* d_in, const int* in_sizes, int n_in,
                              void* d_out, int out_size, void* d_ws, size_t ws_size,
                              hipStream_t stream) {
  (void)in_sizes; (void)n_in; (void)out_size; (void)ws_size;
  const float* query  = (const float*)d_in[0];
  const float* q_w    = (const float*)d_in[1];
  const float* q_b    = (const float*)d_in[2];
  const float* k_w    = (const float*)d_in[3];
  const float* k_b    = (const float*)d_in[4];
  const float* v_w    = (const float*)d_in[5];
  const float* v_b    = (const float*)d_in[6];
  const float* out_w  = (const float*)d_in[7];
  const float* out_b  = (const float*)d_in[8];
  const float* rel_emb= (const float*)d_in[9];
  const float* grep_w = (const float*)d_in[10];
  const float* grep_b = (const float*)d_in[11];
  const float* grep_a = (const float*)d_in[12];

  char* ws = (char*)d_ws;
  const size_t MB = 1ull << 20;
  u16* qbf  = (u16*)(ws + 0 * MB);      // 8MB  query bf16 (t,b,e)
  u16* wqb  = (u16*)(ws + 8 * MB);      // 2MB
  u16* wkb  = (u16*)(ws + 10 * MB);
  u16* wvb  = (u16*)(ws + 12 * MB);
  u16* wob  = (u16*)(ws + 14 * MB);
  u16* qav  = (u16*)(ws + 16 * MB);     // 8MB  [b,h,t,d] (log2-scaled Q)
  u16* kstg = (u16*)(ws + 24 * MB);     // 8MB  fragment-major K tiles
  u16* vstg = (u16*)(ws + 32 * MB);     // 8MB  fragment-major V tiles
  u16* aout = (u16*)(ws + 40 * MB);     // 8MB  attn out (t,b,e) bf16
  float* lut  = (float*)(ws + 48 * MB);              // 256KB [h][4096], log2 dom
  float* gate = (float*)(ws + 48 * MB + 256 * 1024); // 256KB [b,h,t]

  prepk<<<dim3(8464), 256, 0, stream>>>(query, q_w, k_w, v_w, out_w, rel_emb,
                                        grep_w, grep_b, grep_a,
                                        qbf, wqb, wkb, wvb, wob, lut, gate);

  gemmk<0, 3><<<dim3(16, 64), 256, 0, stream>>>(qbf, wqb, wkb, wvb, q_b, k_b, v_b,
                                                qav, kstg, vstg, nullptr);
  flashk<<<dim3(512), 256, 0, stream>>>(qav, kstg, vstg, lut, gate, aout);
  gemmk<3, 1><<<dim3(16, 64), 256, 0, stream>>>(aout, wob, wob, wob, out_b, out_b, out_b,
                                                nullptr, nullptr, nullptr, (float*)d_out);
}

// Round 18
// 136.862 us; speedup vs baseline: 1.0092x; 1.0092x over previous
//
#include <hip/hip_runtime.h>
#include <math.h>

typedef unsigned short u16;
typedef unsigned int u32;
typedef __bf16 bf16x8 __attribute__((ext_vector_type(8)));
typedef float f32x4 __attribute__((ext_vector_type(4)));
typedef float f32x16 __attribute__((ext_vector_type(16)));

// ---------- helpers ----------
__device__ __forceinline__ u32 f2bf(float f) {
  union { float f; u32 u; } v; v.f = f;
  u32 r = v.u + 0x7fffu + ((v.u >> 16) & 1u);
  return r >> 16;
}

__device__ __forceinline__ u32 pkbf(float a, float b) {
  u32 r;
  asm("v_cvt_pk_bf16_f32 %0, %1, %2" : "=v"(r) : "v"(a), "v"(b));
  return r;
}

// v_exp_f32 computes 2^x (log2 domain)
__device__ __forceinline__ float ex2(float x) {
  float r;
  asm("v_exp_f32 %0, %1" : "=v"(r) : "v"(x));
  return r;
}

// async global->LDS, 16B per lane. LDS dest wave-uniform base; HW adds lane*16.
__device__ __forceinline__ void gld16(const void* g, void* s) {
  __builtin_amdgcn_global_load_lds(
      reinterpret_cast<__attribute__((address_space(1))) u32*>((size_t)g),
      reinterpret_cast<__attribute__((address_space(3))) u32*>((u32)(size_t)s),
      16, 0, 0);
}

// ---------- prep: all conversions + lut + gate in ONE launch ----------
__global__ __launch_bounds__(256) void prepk(
    const float* __restrict__ query, const float* __restrict__ q_w,
    const float* __restrict__ k_w, const float* __restrict__ v_w,
    const float* __restrict__ out_w, const float* __restrict__ rel_emb,
    const float* __restrict__ grep_w, const float* __restrict__ grep_b,
    const float* __restrict__ grep_a,
    u16* __restrict__ qbf, u16* __restrict__ wqb, u16* __restrict__ wkb,
    u16* __restrict__ wvb, u16* __restrict__ wob,
    float* __restrict__ lut, float* __restrict__ gate) {
  const int bid = blockIdx.x, tid = threadIdx.x;
  if (bid < 8192) {
    const float* src; u16* dst; int i0;
    if (bid < 4096)      { src = query; dst = qbf; i0 = bid; }
    else if (bid < 5120) { src = q_w;   dst = wqb; i0 = bid - 4096; }
    else if (bid < 6144) { src = k_w;   dst = wkb; i0 = bid - 5120; }
    else if (bid < 7168) { src = v_w;   dst = wvb; i0 = bid - 6144; }
    else                 { src = out_w; dst = wob; i0 = bid - 7168; }
    const int i = i0 * 256 + tid;
    float4 v = ((const float4*)src)[i];
    uint2 o;
    o.x = f2bf(v.x) | (f2bf(v.y) << 16);
    o.y = f2bf(v.z) | (f2bf(v.w) << 16);
    ((uint2*)dst)[i] = o;
  } else if (bid < 8208) {
    const int dix = (bid - 8192) * 256 + tid;
    int rp = dix - 2048;                 // rp = s - t
    int bucket = (rp > 0) ? 16 : 0;
    int rpa = rp < 0 ? -rp : rp;
    if (rpa < 8) {
      bucket += rpa;
    } else {
      int large = 8 + (int)(logf((float)rpa * 0.125f) * (8.0f / 2.772588722239781f));
      bucket += (large < 15) ? large : 15;
    }
    const float LOG2E = 1.4426950408889634f;
#pragma unroll
    for (int h = 0; h < 16; ++h) lut[h * 4096 + dix] = rel_emb[bucket * 16 + h] * LOG2E;
  } else {
    __shared__ __align__(16) float gw[8][64];
    __shared__ float gb[8];
    __shared__ float ga[16];
    if (tid < 128) ((float4*)&gw[0][0])[tid] = ((const float4*)grep_w)[tid];
    if (tid < 8) gb[tid] = grep_b[tid];
    if (tid < 16) ga[tid] = grep_a[tid];
    __syncthreads();
    const int i = (bid - 8208) * 256 + tid;  // i = ((b*16+h)*2048 + t)
    const int t = i & 2047, h = (i >> 11) & 15, b = i >> 15;
    const float* x = query + ((size_t)t * 2 + b) * 1024 + h * 64;
    float acc[8] = {0, 0, 0, 0, 0, 0, 0, 0};
    for (int e4 = 0; e4 < 16; ++e4) {
      float4 xv = ((const float4*)x)[e4];
#pragma unroll
      for (int j = 0; j < 8; ++j)
        acc[j] += xv.x * gw[j][e4 * 4] + xv.y * gw[j][e4 * 4 + 1] +
                  xv.z * gw[j][e4 * 4 + 2] + xv.w * gw[j][e4 * 4 + 3];
    }
    float sA = acc[0] + acc[1] + acc[2] + acc[3] + gb[0] + gb[1] + gb[2] + gb[3];
    float sB = acc[4] + acc[5] + acc[6] + acc[7] + gb[4] + gb[5] + gb[6] + gb[7];
    float gA = 1.0f / (1.0f + expf(-sA));
    float gB = 1.0f / (1.0f + expf(-sB));
    gate[i] = gA * (gB * ga[h] - 1.0f) + 2.0f;
  }
}

// ---------- GEMM: fused-QKV 64x64 tiles, BK=64; A staged ONCE for NMODE weight mats ----------
// MB+mm = mode: 0 q->qa*QSC ; 1 k->kstage ; 2 v->vstage ; 3 out-proj->fout fp32
// kstage[bh][tile(64)][slot(8)][srow(32)][8] ; vstage[bh][tile(64)][slot(4)][d(64)][8]
template <int MB, int NM>
__global__ __launch_bounds__(256) void gemmk(
    const u16* __restrict__ A,
    const u16* __restrict__ W0, const u16* __restrict__ W1, const u16* __restrict__ W2,
    const float* __restrict__ b0, const float* __restrict__ b1, const float* __restrict__ b2,
    u16* __restrict__ qa, u16* __restrict__ kst, u16* __restrict__ vst,
    float* __restrict__ fout) {
  __shared__ __align__(16) u16 As[64 * 64];        // 8KB  [row][64], slot^=(row&7)
  __shared__ __align__(16) u16 Bs[NM][64 * 64];    // 8KB per mode

  const int tid = threadIdx.x;
  const int l = tid & 63;
  const int w = tid >> 6;
  const int wr = w >> 1, wc = w & 1;               // wave quadrant: rows wr*32, cols wc*32
  const int m0 = blockIdx.y * 64, n0 = blockIdx.x * 64;
  const int li = l >> 3, ls = l & 7;
  const u16* const Ws[3] = {W0, W1, W2};
  const float* const bs[3] = {b0, b1, b2};

  f32x4 acc[NM][2][2] = {};

  for (int k0 = 0; k0 < 1024; k0 += 64) {
#pragma unroll
    for (int j = 0; j < 2; ++j) {
      const int rr = w * 16 + j * 8 + li;
      const int cs = ls ^ (rr & 7);                // inverse-swizzled source slot
      gld16(A + ((size_t)(m0 + rr) << 10) + k0 + cs * 8, &As[(w * 16 + j * 8) * 64]);
#pragma unroll
      for (int mm = 0; mm < NM; ++mm)
        gld16(Ws[mm] + ((size_t)(n0 + rr) << 10) + k0 + cs * 8, &Bs[mm][(w * 16 + j * 8) * 64]);
    }
    __syncthreads();
#pragma unroll
    for (int ks = 0; ks < 2; ++ks) {
      bf16x8 af[2];
#pragma unroll
      for (int mf = 0; mf < 2; ++mf) {
        const int row = wr * 32 + mf * 16 + (l & 15);
        const int slot = (ks * 4 + (l >> 4)) ^ (row & 7);
        af[mf] = *(const bf16x8*)&As[row * 64 + slot * 8];
      }
#pragma unroll
      for (int mm = 0; mm < NM; ++mm) {
        bf16x8 bfr[2];
#pragma unroll
        for (int nf = 0; nf < 2; ++nf) {
          const int row = wc * 32 + nf * 16 + (l & 15);
          const int slot = (ks * 4 + (l >> 4)) ^ (row & 7);
          bfr[nf] = *(const bf16x8*)&Bs[mm][row * 64 + slot * 8];
        }
#pragma unroll
        for (int mf = 0; mf < 2; ++mf)
#pragma unroll
          for (int nf = 0; nf < 2; ++nf)
            acc[mm][mf][nf] = __builtin_amdgcn_mfma_f32_16x16x32_bf16(af[mf], bfr[nf], acc[mm][mf][nf], 0, 0, 0);
      }
    }
    __syncthreads();
  }

  const float QSC = 0.125f * 1.4426950408889634f;  // HD^-0.5 * log2(e): Q in log2 domain
#pragma unroll
  for (int mm = 0; mm < NM; ++mm) {
    const int mode = MB + mm;                      // compile-time
    const float* bias = bs[mm];
#pragma unroll
    for (int mf = 0; mf < 2; ++mf)
#pragma unroll
      for (int nf = 0; nf < 2; ++nf)
#pragma unroll
        for (int r = 0; r < 4; ++r) {
          const int row = m0 + wr * 32 + mf * 16 + (l >> 4) * 4 + r;  // m = t*2+b
          const int col = n0 + wc * 32 + nf * 16 + (l & 15);          // n = h*64+d
          float v = acc[mm][mf][nf][r] + bias[col];
          const int t = row >> 1, bb = row & 1, hh = col >> 6, d = col & 63;
          const size_t bh = (size_t)bb * 16 + hh;
          if (mode == 0) {
            v *= QSC;
            qa[((bh * 2048 + t) << 6) + d] = (u16)f2bf(v);
          } else if (mode == 1) {
            kst[((bh * 64 + (t >> 5)) << 11) + ((d >> 3) << 8) + ((t & 31) << 3) + (d & 7)] = (u16)f2bf(v);
          } else if (mode == 2) {
            vst[((bh * 64 + (t >> 5)) << 11) + (((t >> 3) & 3) << 9) + (d << 3) + (t & 7)] = (u16)f2bf(v);
          } else {
            fout[((size_t)row << 10) + col] = v;
          }
        }
  }
}

// ---------- flash attention v10: R12 structure + KVBLK=64 pairing (half the barriers) ----------
// Block = 128 q-rows, 4 waves (2 halves x 2 subs); wave owns TWO 32-row q-tiles over its
// 1024-KV half. LDS buffers hold a PAIR of consecutive K/V tiles (8KB each, contiguous in
// kstage/vstage -> 8 linear gld16/wave); prefetch pair t+1 at top of pair t; two R12-inner
// iterations per pair; ONE __syncthreads per pair (16 vs 32). Same buffer-reuse invariant
// as R9/R12. 2-way m/l/O combine in LDS at the end.
__global__ __launch_bounds__(256, 2) void flashk(const u16* __restrict__ qa,
                                                 const u16* __restrict__ kst,
                                                 const u16* __restrict__ vst,
                                                 const float* __restrict__ lutg,
                                                 const float* __restrict__ gatew,
                                                 u16* __restrict__ aout) {
  const int B = blockIdx.x;
  const int xcd = B & 7, j = B >> 3;
  const int bh = xcd * 4 + (j >> 4);       // 4 heads per XCD (K/V L2-resident)
  const int qt = j & 15;
  const int hh = bh & 15, b = bh >> 4;
  const int tid = threadIdx.x, l = tid & 63, w = tid >> 6;
  const int half = w >> 1, sub = w & 1;
  const int hi = l >> 5, q = l & 31;
  const int q0b = qt * 128;
  const int qr0 = q0b + sub * 32;          // q-tile 0 base
  const int qr1 = q0b + 64 + sub * 32;     // q-tile 1 base

  __shared__ union {
    struct { u16 K[2][2][4096]; u16 V[2][2][4096]; } m;   // 64KB: [half][buf][pair of tiles]
    struct { float pO[2][2][32][68]; } c;                 // combine 34.8KB
  } S;
  __shared__ float pm[2][2][32], pl[2][2][32];
  __shared__ __align__(16) float slice[288];   // lut band, dix0=1920 -> s-t in [-128,160)

  for (int i = tid; i < 288; i += 256) slice[i] = lutg[hh * 4096 + 1920 + i];

  const size_t tb0 = (size_t)bh * 64;      // tile index base
  const u16* Q = qa + ((size_t)bh << 17);

  // Q B-frags + per-tile state
  bf16x8 qf[2][4];
  float g[2], m_run[2], l_run[2];
  f32x16 oacc[2][2] = {};                  // [qi][dt]
#pragma unroll
  for (int qi = 0; qi < 2; ++qi) {
    const int qg = (qi ? qr1 : qr0) + q;
#pragma unroll
    for (int mk = 0; mk < 4; ++mk)
      qf[qi][mk] = *(const bf16x8*)&Q[((size_t)qg << 6) + mk * 16 + hi * 8];
    g[qi] = gatew[((size_t)bh << 11) + qg];
    m_run[qi] = -3e38f;
    l_run[qi] = 0.0f;
  }
  const float lutm = lutg[hh * 4096];          // far-minus lut value (log2 dom)
  const float lutp = lutg[hh * 4096 + 4095];   // far-plus lut value

  // prologue: stage pair 0 (tiles 0,1 of this half) into buf 0. Linear lane*16B.
  {
    const u16* kt0 = kst + ((tb0 + half * 32) << 11) + l * 8;
    const u16* vt0 = vst + ((tb0 + half * 32) << 11) + l * 8;
    if (sub == 0) {
#pragma unroll
      for (int i = 0; i < 8; ++i) gld16(kt0 + i * 512, &S.m.K[half][0][i * 512]);
    } else {
#pragma unroll
      for (int i = 0; i < 8; ++i) gld16(vt0 + i * 512, &S.m.V[half][0][i * 512]);
    }
  }
  __syncthreads();

  for (int tp = 0; tp < 16; ++tp) {
    const int buf = tp & 1;
    // prefetch next PAIR into other buffer (two contiguous tiles = 8 linear gld16)
    if (tp < 15) {
      const u16* ktn = kst + ((tb0 + half * 32 + (tp + 1) * 2) << 11) + l * 8;
      const u16* vtn = vst + ((tb0 + half * 32 + (tp + 1) * 2) << 11) + l * 8;
      if (sub == 0) {
#pragma unroll
        for (int i = 0; i < 8; ++i) gld16(ktn + i * 512, &S.m.K[half][buf ^ 1][i * 512]);
      } else {
#pragma unroll
        for (int i = 0; i < 8; ++i) gld16(vtn + i * 512, &S.m.V[half][buf ^ 1][i * 512]);
      }
    }

#pragma unroll
    for (int st = 0; st < 2; ++st) {
      const int ts = tp * 2 + st;
      const u16* Kb = &S.m.K[half][buf][st * 2048];
      const u16* Vb = &S.m.V[half][buf][st * 2048];
      const int s0 = half * 1024 + ts * 32;

      // K frags load ONCE, serve both q-tiles
      bf16x8 kf[4];
#pragma unroll
      for (int mk = 0; mk < 4; ++mk)
        kf[mk] = *(const bf16x8*)&Kb[(mk * 2 + hi) * 256 + q * 8];

      bf16x8 pa[2][2];
#pragma unroll
      for (int qi = 0; qi < 2; ++qi) {
        const int qrb = qi ? qr1 : qr0;
        // S^T tile: C[k_local][q], k_local = (reg&3)+8*(reg>>2)+4*hi
        f32x16 s = {};
#pragma unroll
        for (int mk = 0; mk < 4; ++mk)
          s = __builtin_amdgcn_mfma_f32_32x32x16_bf16(kf[mk], qf[qi][mk], s, 0, 0, 0);

        const int kt = (s0 - qrb) >> 5;
        const bool far = (kt <= -4) | (kt >= 4);
        float gc = 0.0f;
        float mx;
        if (far) {
          gc = ((kt < 0) ? lutm : lutp) * g[qi];
          float t0_ = fmaxf(fmaxf(s[0], s[1]), s[2]);
          float t1_ = fmaxf(fmaxf(s[3], s[4]), s[5]);
          float t2_ = fmaxf(fmaxf(s[6], s[7]), s[8]);
          float t3_ = fmaxf(fmaxf(s[9], s[10]), s[11]);
          float t4_ = fmaxf(fmaxf(s[12], s[13]), s[14]);
          mx = fmaxf(fmaxf(fmaxf(t0_, t1_), t2_), fmaxf(fmaxf(t3_, t4_), s[15]));
          mx = fmaxf(mx, __shfl_xor(mx, 32, 64)) + gc;
        } else {
          const int sb = s0 - qrb + 128 + 4 * hi - q;
#pragma unroll
          for (int reg = 0; reg < 16; ++reg) {
            const int kloc = (reg & 3) + 8 * (reg >> 2);
            s[reg] = fmaf(g[qi], slice[sb + kloc], s[reg]);
          }
          float t0_ = fmaxf(fmaxf(s[0], s[1]), s[2]);
          float t1_ = fmaxf(fmaxf(s[3], s[4]), s[5]);
          float t2_ = fmaxf(fmaxf(s[6], s[7]), s[8]);
          float t3_ = fmaxf(fmaxf(s[9], s[10]), s[11]);
          float t4_ = fmaxf(fmaxf(s[12], s[13]), s[14]);
          mx = fmaxf(fmaxf(fmaxf(t0_, t1_), t2_), fmaxf(fmaxf(t3_, t4_), s[15]));
          mx = fmaxf(mx, __shfl_xor(mx, 32, 64));
        }
        // defer-max (T13), log2 domain threshold ~ 8*log2e
        if (!__all(mx - m_run[qi] <= 11.5f)) {
          const float mnew = fmaxf(m_run[qi], mx);
          const float sc = ex2(m_run[qi] - mnew);
          l_run[qi] *= sc;
#pragma unroll
          for (int r = 0; r < 16; ++r) { oacc[qi][0][r] *= sc; oacc[qi][1][r] *= sc; }
          m_run[qi] = mnew;
        }
        // P = 2^(S - mref), tree row-sum
        const float mref = m_run[qi] - gc;
#pragma unroll
        for (int reg = 0; reg < 16; ++reg) s[reg] = ex2(s[reg] - mref);
        {
          float r0 = (s[0] + s[1]) + (s[2] + s[3]);
          float r1 = (s[4] + s[5]) + (s[6] + s[7]);
          float r2 = (s[8] + s[9]) + (s[10] + s[11]);
          float r3 = (s[12] + s[13]) + (s[14] + s[15]);
          float rsum = (r0 + r1) + (r2 + r3);
          rsum += __shfl_xor(rsum, 32, 64);
          l_run[qi] += rsum;
        }
        // pack P -> PV B-frags (T12, shfl-proven exchange)
#pragma unroll
        for (int kh = 0; kh < 2; ++kh) {
          const int rb = kh * 8;
          const u32 X0 = pkbf(s[rb + 0], s[rb + 1]);
          const u32 X1 = pkbf(s[rb + 2], s[rb + 3]);
          const u32 Y0 = pkbf(s[rb + 4], s[rb + 5]);
          const u32 Y1 = pkbf(s[rb + 6], s[rb + 7]);
          const u32 E0 = hi ? X0 : Y0;
          const u32 E1 = hi ? X1 : Y1;
          const u32 Ep0 = (u32)__shfl_xor((int)E0, 32, 64);
          const u32 Ep1 = (u32)__shfl_xor((int)E1, 32, 64);
          union { u32 wds[4]; bf16x8 v; } pu;
          pu.wds[0] = hi ? Ep0 : X0;
          pu.wds[1] = hi ? Ep1 : X1;
          pu.wds[2] = hi ? Y0 : Ep0;
          pu.wds[3] = hi ? Y1 : Ep1;
          pa[qi][kh] = pu.v;
        }
      }
      // V frags load ONCE, serve both q-tiles
      bf16x8 vf[4];
#pragma unroll
      for (int i2 = 0; i2 < 4; ++i2) {     // i2 = dt*2+kh
        const int dt = i2 >> 1, kh = i2 & 1;
        vf[i2] = *(const bf16x8*)&Vb[(kh * 2 + hi) * 512 + dt * 256 + q * 8];
      }
      // O^T += V^T . P for both q-tiles
#pragma unroll
      for (int qi = 0; qi < 2; ++qi)
#pragma unroll
        for (int dt = 0; dt < 2; ++dt)
#pragma unroll
          for (int kh = 0; kh < 2; ++kh)
            oacc[qi][dt] = __builtin_amdgcn_mfma_f32_32x32x16_bf16(vf[dt * 2 + kh], pa[qi][kh], oacc[qi][dt], 0, 0, 0);
    }
    __syncthreads();   // pair t+1 staged (vmcnt drained); all waves done with buf
  }

  // ---- 2-way combine: pairs (half0,sub) <-> (half1,sub), both q-tiles ----
  __syncthreads();   // all K/V reads done; repurpose LDS union
  if (half == 1) {
    if (hi == 0) {
      pm[sub][0][q] = m_run[0]; pl[sub][0][q] = l_run[0];
      pm[sub][1][q] = m_run[1]; pl[sub][1][q] = l_run[1];
    }
#pragma unroll
    for (int qi = 0; qi < 2; ++qi)
#pragma unroll
      for (int dt = 0; dt < 2; ++dt)
#pragma unroll
        for (int g4 = 0; g4 < 4; ++g4) {
          float4 v4;
          v4.x = oacc[qi][dt][g4 * 4 + 0];
          v4.y = oacc[qi][dt][g4 * 4 + 1];
          v4.z = oacc[qi][dt][g4 * 4 + 2];
          v4.w = oacc[qi][dt][g4 * 4 + 3];
          *(float4*)&S.c.pO[sub][qi][q][dt * 32 + g4 * 8 + hi * 4] = v4;
        }
  }
  __syncthreads();
  if (half == 0) {
#pragma unroll
    for (int qi = 0; qi < 2; ++qi) {
      const float mB = pm[sub][qi][q], lB = pl[sub][qi][q];
      const float M = fmaxf(m_run[qi], mB);
      const float eA = ex2(m_run[qi] - M), eB = ex2(mB - M);
      const float inv = 1.0f / (l_run[qi] * eA + lB * eB);
      const int qg = (qi ? qr1 : qr0) + q;
#pragma unroll
      for (int dt = 0; dt < 2; ++dt)
#pragma unroll
        for (int gph = 0; gph < 4; ++gph) {
          const int d0 = dt * 32 + gph * 8 + hi * 4;
          const float4 p4 = *(const float4*)&S.c.pO[sub][qi][q][d0];
          const float o0 = (oacc[qi][dt][gph * 4 + 0] * eA + p4.x * eB) * inv;
          const float o1 = (oacc[qi][dt][gph * 4 + 1] * eA + p4.y * eB) * inv;
          const float o2 = (oacc[qi][dt][gph * 4 + 2] * eA + p4.z * eB) * inv;
          const float o3 = (oacc[qi][dt][gph * 4 + 3] * eA + p4.w * eB) * inv;
          uint2 st;
          st.x = pkbf(o0, o1);
          st.y = pkbf(o2, o3);
          *(uint2*)&aout[(((size_t)qg * 2 + b) << 10) + hh * 64 + d0] = st;
        }
    }
  }
}

// ---------- launch ----------
extern "C" void kernel_launch(void* const* d_in, const int* in_sizes, int n_in,
                              void* d_out, int out_size, void* d_ws, size_t ws_size,
                              hipStream_t stream) {
  (void)in_sizes; (void)n_in; (void)out_size; (void)ws_size;
  const float* query  = (const float*)d_in[0];
  const float* q_w    = (const float*)d_in[1];
  const float* q_b    = (const float*)d_in[2];
  const float* k_w    = (const float*)d_in[3];
  const float* k_b    = (const float*)d_in[4];
  const float* v_w    = (const float*)d_in[5];
  const float* v_b    = (const float*)d_in[6];
  const float* out_w  = (const float*)d_in[7];
  const float* out_b  = (const float*)d_in[8];
  const float* rel_emb= (const float*)d_in[9];
  const float* grep_w = (const float*)d_in[10];
  const float* grep_b = (const float*)d_in[11];
  const float* grep_a = (const float*)d_in[12];

  char* ws = (char*)d_ws;
  const size_t MB = 1ull << 20;
  u16* qbf  = (u16*)(ws + 0 * MB);      // 8MB  query bf16 (t,b,e)
  u16* wqb  = (u16*)(ws + 8 * MB);      // 2MB
  u16* wkb  = (u16*)(ws + 10 * MB);
  u16* wvb  = (u16*)(ws + 12 * MB);
  u16* wob  = (u16*)(ws + 14 * MB);
  u16* qav  = (u16*)(ws + 16 * MB);     // 8MB  [b,h,t,d] (log2-scaled Q)
  u16* kstg = (u16*)(ws + 24 * MB);     // 8MB  fragment-major K tiles
  u16* vstg = (u16*)(ws + 32 * MB);     // 8MB  fragment-major V tiles
  u16* aout = (u16*)(ws + 40 * MB);     // 8MB  attn out (t,b,e) bf16
  float* lut  = (float*)(ws + 48 * MB);              // 256KB [h][4096], log2 dom
  float* gate = (float*)(ws + 48 * MB + 256 * 1024); // 256KB [b,h,t]

  prepk<<<dim3(8464), 256, 0, stream>>>(query, q_w, k_w, v_w, out_w, rel_emb,
                                        grep_w, grep_b, grep_a,
                                        qbf, wqb, wkb, wvb, wob, lut, gate);

  gemmk<0, 3><<<dim3(16, 64), 256, 0, stream>>>(qbf, wqb, wkb, wvb, q_b, k_b, v_b,
                                                qav, kstg, vstg, nullptr);
  flashk<<<dim3(512), 256, 0, stream>>>(qav, kstg, vstg, lut, gate, aout);
  gemmk<3, 1><<<dim3(16, 64), 256, 0, stream>>>(aout, wob, wob, wob, out_b, out_b, out_b,
                                                nullptr, nullptr, nullptr, (float*)d_out);
}